// Round 1
// baseline (11635.227 us; speedup 1.0000x reference)
//
#include <hip/hip_runtime.h>
#include <math.h>

#define N_TOK   131072
#define NE      1024
#define EDIM    256
#define MARGIN  1.0e-4f // ulp(256..512)=3.05e-5 + 2*screen_err(~1.4e-5) w/ 2x safety

// Screen kernel geometry: 64 x-rows/block (K=256 resident in LDS),
// codebook streamed as 4 tiles of 256 codes x 8 chunks of K=32 (dbuf).
#define BM      64
#define BN      256
#define BK      32
#define LDW     36      // BK + 4 pad floats: stride 144B = 4 mod 32 banks -> conflict-free b128
#define NPHASE  32      // (NE/BN) * (EDIM/BK)

// ---------------------------------------------------------------------------
// numpy pairwise sum replica for sum(v*v) over 256 contiguous floats.
// (verbatim from validated kernel — do not touch)
__device__ __forceinline__ float np_sumsq_256(const float* q) {
    float b[2];
#pragma unroll
    for (int blk = 0; blk < 2; ++blk) {
        const float* a = q + blk * 128;
        float r0 = __fmul_rn(a[0], a[0]), r1 = __fmul_rn(a[1], a[1]);
        float r2 = __fmul_rn(a[2], a[2]), r3 = __fmul_rn(a[3], a[3]);
        float r4 = __fmul_rn(a[4], a[4]), r5 = __fmul_rn(a[5], a[5]);
        float r6 = __fmul_rn(a[6], a[6]), r7 = __fmul_rn(a[7], a[7]);
        for (int i = 8; i < 128; i += 8) {
            r0 = __fadd_rn(r0, __fmul_rn(a[i + 0], a[i + 0]));
            r1 = __fadd_rn(r1, __fmul_rn(a[i + 1], a[i + 1]));
            r2 = __fadd_rn(r2, __fmul_rn(a[i + 2], a[i + 2]));
            r3 = __fadd_rn(r3, __fmul_rn(a[i + 3], a[i + 3]));
            r4 = __fadd_rn(r4, __fmul_rn(a[i + 4], a[i + 4]));
            r5 = __fadd_rn(r5, __fmul_rn(a[i + 5], a[i + 5]));
            r6 = __fadd_rn(r6, __fmul_rn(a[i + 6], a[i + 6]));
            r7 = __fadd_rn(r7, __fmul_rn(a[i + 7], a[i + 7]));
        }
        b[blk] = __fadd_rn(__fadd_rn(__fadd_rn(r0, r1), __fadd_rn(r2, r3)),
                           __fadd_rn(__fadd_rn(r4, r5), __fadd_rn(r6, r7)));
    }
    return __fadd_rn(b[0], b[1]);
}

// ---------------------------------------------------------------------------
// Kernel 0: sw2f[c] = np-replica fp32 of sum(w_c^2). Also zeroes rescue count.
__global__ void sw2_np_kernel(const float* __restrict__ w, float* __restrict__ sw2,
                              int* __restrict__ rcount) {
    int row = blockIdx.x * 256 + threadIdx.x;
    sw2[row] = np_sumsq_256(&w[row * EDIM]);
    if (row == 0) *rcount = 0;
}

// ---------------------------------------------------------------------------
// w-chunk staging helpers: chunk p -> tile tau = p>>3, k-chunk kc = p&7.
// 256 codes x 32 floats = 32KB per chunk; 8 float4 per thread.
__device__ __forceinline__ void load_w_regs(const float* __restrict__ w, int p,
                                            int t, float4 r[8]) {
    const int tau = p >> 3, kc = p & 7;
#pragma unroll
    for (int q = 0; q < 8; ++q) {
        int e   = t + 256 * q;          // float4 index in chunk
        int row = e >> 3;               // 8 float4 per code row
        int c4  = e & 7;
        r[q] = *(const float4*)&w[(tau * 256 + row) * EDIM + kc * BK + 4 * c4];
    }
}

__device__ __forceinline__ void store_w_lds(float* __restrict__ wsb, int t,
                                            const float4 r[8]) {
#pragma unroll
    for (int q = 0; q < 8; ++q) {
        int e   = t + 256 * q;
        int row = e >> 3;
        int c4  = e & 7;
        *(float4*)&wsb[row * LDW + 4 * c4] = r[q];
    }
}

// ---------------------------------------------------------------------------
// Kernel 1: screen. x-tile K-resident in LDS (loaded once), w double-buffered.
// 256 threads; micro-tile 8 rows x 8 codes. Near-ties appended to rlist.
__global__ __launch_bounds__(256, 1) void screen_kernel(
    const float* __restrict__ x, const float* __restrict__ w,
    const float* __restrict__ sw2, float* __restrict__ idxo,
    int* __restrict__ rlist, int* __restrict__ rcount)
{
    __shared__ float xs[BM * EDIM];        // 64 KB, linear, reads are broadcast
    __shared__ float ws[2][BN * LDW];      // 2 x 36 KB double buffer
    __shared__ float sws[NE];              // 4 KB sw2 copy

    const int t  = threadIdx.x;
    const int tx = t & 31;                 // code-group lane (32)
    const int ty = t >> 5;                 // row group (8)
    const size_t row0 = (size_t)blockIdx.x * BM;

    // stage x tile once (linear 64 KB copy) + sw2
    {
        const float4* xsrc = (const float4*)(x + row0 * EDIM);
#pragma unroll
        for (int q = 0; q < 16; ++q)
            ((float4*)xs)[t + 256 * q] = xsrc[t + 256 * q];
#pragma unroll
        for (int q = 0; q < 4; ++q) sws[t + 256 * q] = sw2[t + 256 * q];
    }
    float4 stg[8];
    load_w_regs(w, 0, t, stg);
    store_w_lds(ws[0], t, stg);
    __syncthreads();

    float bestv[8], secv[8];
    int   besti[8];
#pragma unroll
    for (int i = 0; i < 8; ++i) { bestv[i] = 3.4e38f; secv[i] = 3.4e38f; besti[i] = 0; }

    float acc[8][8];

    for (int p = 0; p < NPHASE; ++p) {
        const int buf = p & 1;
        const int kc  = p & 7;
        if (kc == 0) {
#pragma unroll
            for (int i = 0; i < 8; ++i)
#pragma unroll
                for (int j = 0; j < 8; ++j) acc[i][j] = 0.f;
        }
        if (p < NPHASE - 1) load_w_regs(w, p + 1, t, stg);   // issue early

        const float* wsb = ws[buf];
#pragma unroll
        for (int k4 = 0; k4 < 8; ++k4) {
            float4 xv[8], wv[8];
#pragma unroll
            for (int i = 0; i < 8; ++i)
                xv[i] = *(const float4*)&xs[(ty + 8 * i) * EDIM + kc * BK + 4 * k4];
#pragma unroll
            for (int j = 0; j < 8; ++j)
                wv[j] = *(const float4*)&wsb[(tx + 32 * j) * LDW + 4 * k4];
#pragma unroll
            for (int i = 0; i < 8; ++i)
#pragma unroll
                for (int j = 0; j < 8; ++j)
                    acc[i][j] += xv[i].x * wv[j].x + xv[i].y * wv[j].y
                               + xv[i].z * wv[j].z + xv[i].w * wv[j].w;
        }
        if (p < NPHASE - 1) store_w_lds(ws[buf ^ 1], t, stg); // write late (vmcnt here)
        __syncthreads();

        if (kc == 7) {                                        // tile complete: score
            const int tau = p >> 3;
#pragma unroll
            for (int j = 0; j < 8; ++j) {
                int c = tau * 256 + tx + 32 * j;
                float s2 = sws[c];
#pragma unroll
                for (int i = 0; i < 8; ++i) {
                    float d = s2 - 2.f * acc[i][j];
                    if (d < bestv[i]) { secv[i] = bestv[i]; bestv[i] = d; besti[i] = c; }
                    else if (d < secv[i]) secv[i] = d;
                }
            }
        }
    }

    // exact 2-min merge across the 32 code lanes (same-ty half-wave)
#pragma unroll
    for (int i = 0; i < 8; ++i) {
        float v = bestv[i], s = secv[i];
        int   bi = besti[i];
#pragma unroll
        for (int off = 16; off > 0; off >>= 1) {
            float ov = __shfl_down(v, off, 32);
            float os = __shfl_down(s, off, 32);
            int   oi = __shfl_down(bi, off, 32);
            if (ov < v || (ov == v && oi < bi)) { s = fminf(os, v); v = ov; bi = oi; }
            else                                { s = fminf(s, ov); }
        }
        if (tx == 0) {
            int r = ty + 8 * i;
            idxo[row0 + r] = (float)bi;
            if (s - v < MARGIN) {
                int pos = atomicAdd(rcount, 1);
                rlist[pos] = (int)(row0 + r);
            }
        }
    }
}

// ---------------------------------------------------------------------------
// Kernel 2: rescue. One block per flagged row (grid-stride over compact list).
// Math verbatim from the validated in-block rescue.
__global__ __launch_bounds__(256) void rescue_kernel(
    const float* __restrict__ x, const float* __restrict__ w,
    const float* __restrict__ sw2, float* __restrict__ idxo,
    const int* __restrict__ rlist, const int* __restrict__ rcount)
{
    __shared__ float xsr[EDIM];
    __shared__ float sx2sh;
    __shared__ float rrv[4];
    __shared__ int   rri[4];

    const int t = threadIdx.x;
    const int lane = t & 63, wvid = t >> 6;
    const int cnt = *rcount;

    for (int li = blockIdx.x; li < cnt; li += gridDim.x) {
        const int row = rlist[li];
        xsr[t] = x[(size_t)row * EDIM + t];
        __syncthreads();
        if (t == 0) sx2sh = np_sumsq_256(xsr);
        __syncthreads();
        const float sx2f = sx2sh;
        float bestd = 3.4e38f;
        int   bestc = 0;
#pragma unroll
        for (int jj = 0; jj < 4; ++jj) {
            int c = jj * 256 + t;
            const float4* wc = (const float4*)&w[c * EDIM];
            double acc = 0.0;
            for (int k4 = 0; k4 < 64; ++k4) {
                float4 wv = wc[k4];
                float4 xv = *(const float4*)&xsr[4 * k4];
                acc = fma((double)wv.x, (double)xv.x, acc);
                acc = fma((double)wv.y, (double)xv.y, acc);
                acc = fma((double)wv.z, (double)xv.z, acc);
                acc = fma((double)wv.w, (double)xv.w, acc);
            }
            float m  = (float)acc;                        // exact-rounded sgemm value
            float t1 = __fadd_rn(sx2f, sw2[c]);           // (sx2 + sw2) fp32
            float d  = __fsub_rn(t1, __fmul_rn(2.0f, m)); // ... - 2*m  fp32
            if (d < bestd) { bestd = d; bestc = c; }      // jj asc -> low c on ties
        }
#pragma unroll
        for (int off = 32; off > 0; off >>= 1) {
            float od = __shfl_down(bestd, off, 64);
            int   oc = __shfl_down(bestc, off, 64);
            if (od < bestd || (od == bestd && oc < bestc)) { bestd = od; bestc = oc; }
        }
        if (lane == 0) { rrv[wvid] = bestd; rri[wvid] = bestc; }
        __syncthreads();
        if (t == 0) {
            float bv = rrv[0]; int bi = rri[0];
#pragma unroll
            for (int q = 1; q < 4; ++q)
                if (rrv[q] < bv || (rrv[q] == bv && rri[q] < bi)) { bv = rrv[q]; bi = rri[q]; }
            idxo[row] = (float)bi;
        }
        __syncthreads();   // protect xsr before next list entry
    }
}

// ---------------------------------------------------------------------------
// Kernel 3: gather z_q rows from final indices. 64 rows per block.
__global__ __launch_bounds__(256) void gather_kernel(
    const float* __restrict__ w, const float* __restrict__ idxo,
    float* __restrict__ zq)
{
    const int t = threadIdx.x;
    const int g = t >> 6, f = t & 63;
    const size_t base = (size_t)blockIdx.x * 64;
#pragma unroll 4
    for (int rr = 0; rr < 16; ++rr) {
        size_t row = base + rr * 4 + g;
        int ci = (int)idxo[row];
        float4 v = *(const float4*)&w[(size_t)ci * EDIM + 4 * f];
        *(float4*)&zq[row * EDIM + 4 * f] = v;
    }
}

// ---------------------------------------------------------------------------
__global__ __launch_bounds__(256) void ce_kernel(const float* __restrict__ w,
                                                 float* __restrict__ rowres) {
    __shared__ float wj[4 * EDIM];
    __shared__ float redsum[4 * 4];
    __shared__ float diagl[4];

    const int t  = threadIdx.x;
    const int j0 = blockIdx.x * 4;
    {
        int r = t >> 6, f = t & 63;
        *(float4*)&wj[r * EDIM + 4 * f] = *(const float4*)&w[(j0 + r) * EDIM + 4 * f];
    }
    __syncthreads();

    float se[4] = {0.f, 0.f, 0.f, 0.f};
    for (int kk = 0; kk < 4; ++kk) {
        int k = kk * 256 + t;
        const float4* wk = (const float4*)&w[k * EDIM];
        float d[4] = {0.f, 0.f, 0.f, 0.f};
        for (int f = 0; f < 64; ++f) {
            float4 v = wk[f];
#pragma unroll
            for (int r = 0; r < 4; ++r) {
                float4 a = *(const float4*)&wj[r * EDIM + 4 * f];
                d[r] += a.x * v.x + a.y * v.y + a.z * v.z + a.w * v.w;
            }
        }
#pragma unroll
        for (int r = 0; r < 4; ++r) {
            float l = 3.f * d[r];
            se[r] += expf(l);
            if (k == j0 + r) diagl[r] = l;
        }
    }
    const int lane = t & 63, wv = t >> 6;
#pragma unroll
    for (int r = 0; r < 4; ++r) {
        float s = se[r];
#pragma unroll
        for (int off = 32; off > 0; off >>= 1) s += __shfl_down(s, off, 64);
        if (lane == 0) redsum[r * 4 + wv] = s;
    }
    __syncthreads();
    if (t < 4) {
        float S = redsum[t * 4 + 0] + redsum[t * 4 + 1]
                + redsum[t * 4 + 2] + redsum[t * 4 + 3];
        rowres[j0 + t] = diagl[t] - logf(S);
    }
}

// ---------------------------------------------------------------------------
__global__ void loss_final(const float* __restrict__ rowres,
                           const int* __restrict__ idxp,
                           float* __restrict__ lossp) {
    __shared__ float red[4];
    const int t = threadIdx.x;
    float s = rowres[t] + rowres[t + 256] + rowres[t + 512] + rowres[t + 768];
    const int lane = t & 63, wv = t >> 6;
#pragma unroll
    for (int off = 32; off > 0; off >>= 1) s += __shfl_down(s, off, 64);
    if (lane == 0) red[wv] = s;
    __syncthreads();
    if (t == 0) {
        float tot = red[0] + red[1] + red[2] + red[3];
        float ce = -(tot / 1024.f);
        float loss = (*idxp == 0) ? ce : 0.f;
        *lossp = loss;
    }
}

// ---------------------------------------------------------------------------
extern "C" void kernel_launch(void* const* d_in, const int* in_sizes, int n_in,
                              void* d_out, int out_size, void* d_ws, size_t ws_size,
                              hipStream_t stream) {
    (void)in_sizes; (void)n_in; (void)out_size; (void)ws_size;
    const float* x   = (const float*)d_in[0];
    const float* w   = (const float*)d_in[1];
    const int*   idx = (const int*)d_in[2];

    float* outf  = (float*)d_out;
    float* zq    = outf;                                 // 131072*256 f32
    float* idxo  = outf + (size_t)N_TOK * EDIM;          // 131072 f32
    float* lossp = idxo + N_TOK;                         // 1 f32

    float* sw2    = (float*)d_ws;
    float* rowres = sw2 + NE;

    // rescue list + counter live in the TAIL of the zq region: consumed by
    // rescue_kernel, then gather_kernel overwrites all of zq afterwards.
    int* rlist  = (int*)zq + ((size_t)N_TOK * EDIM - N_TOK - 64);
    int* rcount = rlist + N_TOK;

    sw2_np_kernel<<<NE / 256, 256, 0, stream>>>(w, sw2, rcount);
    screen_kernel<<<N_TOK / BM, 256, 0, stream>>>(x, w, sw2, idxo, rlist, rcount);
    rescue_kernel<<<1024, 256, 0, stream>>>(x, w, sw2, idxo, rlist, rcount);
    gather_kernel<<<N_TOK / 64, 256, 0, stream>>>(w, idxo, zq);
    ce_kernel<<<NE / 4, 256, 0, stream>>>(w, rowres);
    loss_final<<<1, 256, 0, stream>>>(rowres, idx, lossp);
}